// Round 10
// baseline (156.704 us; speedup 1.0000x reference)
//
#include <hip/hip_runtime.h>

#define N_NODES 10000
#define E_RAW   320000
#define E_TOT   330000
#define D_IN    256
#define HID     128
#define F1      512
#define D_OUT   256
#define SLOPE   0.2f
#define EBLOCKS 1290  // ceil(E_TOT/256)
#define SCAN_CHUNK 40 // 256*40 >= N_NODES

typedef __attribute__((ext_vector_type(8))) short bf16x8;
typedef __attribute__((ext_vector_type(4))) float f32x4;

__device__ __forceinline__ float bf2f(ushort u) {
    return __uint_as_float(((uint)u) << 16);
}
__device__ __forceinline__ ushort f2bf(float x) {
    uint u = __float_as_uint(x);
    uint r = (u + 0x7FFFu + ((u >> 16) & 1u)) >> 16;
    return (ushort)r;
}
__device__ __forceinline__ float bfu_lo(uint u) { return __uint_as_float(u << 16); }
__device__ __forceinline__ float bfu_hi(uint u) { return __uint_as_float(u & 0xFFFF0000u); }

__device__ __forceinline__ void gload_lds16(const void* g, void* l) {
    __builtin_amdgcn_global_load_lds(
        (const __attribute__((address_space(1))) void*)g,
        (__attribute__((address_space(3))) void*)l, 16, 0, 0);
}

// ---------------- K1: zero scratch ----------------

__global__ __launch_bounds__(256) void k_zero_all(int* __restrict__ deg,
                                                  float* __restrict__ as1,
                                                  float* __restrict__ ad1,
                                                  float* __restrict__ as2,
                                                  float* __restrict__ ad2) {
    int i = blockIdx.x * 256 + threadIdx.x;
    if (i < 4 * N_NODES) { as1[i] = 0.f; ad1[i] = 0.f; }
    if (i < N_NODES) { deg[i] = 0; as2[i] = 0.f; ad2[i] = 0.f; }
}

// ---------------- K2: degree histogram + per-edge rank ----------------

__global__ __launch_bounds__(256) void k_hist(const int* __restrict__ ei,
                                              int* __restrict__ deg,
                                              int* __restrict__ rank) {
    int e = blockIdx.x * 256 + threadIdx.x;
    if (e < E_TOT) {
        int dst = (e < E_RAW) ? ei[E_RAW + e] : (e - E_RAW);
        rank[e] = atomicAdd(&deg[dst], 1);
    }
}

// ---------------- K3: scan (block 0) + coalesced weight transposes + x cast ----------------

__global__ __launch_bounds__(256) void k_prep(const int* __restrict__ deg,
                                              int* __restrict__ row_start,
                                              const float* __restrict__ W1,
                                              ushort* __restrict__ w1h,
                                              const float* __restrict__ W2,
                                              ushort* __restrict__ w2h,
                                              const float* __restrict__ x,
                                              ushort* __restrict__ xb) {
    int b = blockIdx.x;
    int tid = threadIdx.x;
    if (b == 0) {
        __shared__ int tots[256];
        int base = tid * SCAN_CHUNK;
        int loc[SCAN_CHUNK];
        int s = 0;
        #pragma unroll
        for (int k = 0; k < SCAN_CHUNK; k++) {
            int idx = base + k;
            int v = (idx < N_NODES) ? deg[idx] : 0;
            loc[k] = s;
            s += v;
        }
        tots[tid] = s;
        __syncthreads();
        for (int off = 1; off < 256; off <<= 1) {
            int t = (tid >= off) ? tots[tid - off] : 0;
            __syncthreads();
            tots[tid] += t;
            __syncthreads();
        }
        int excl = tots[tid] - s;
        #pragma unroll
        for (int k = 0; k < SCAN_CHUNK; k++) {
            int idx = base + k;
            if (idx < N_NODES) row_start[idx] = excl + loc[k];
        }
        if (tid == 255) row_start[N_NODES] = E_TOT;
    } else if (b <= 64) {
        // W1 [256][512] -> w1h [512][256]; wave task: 64 cols x 8 rows
        int task = (b - 1) * 4 + (tid >> 6);      // 0..255
        int lane = tid & 63;
        int n = (task >> 5) * 64 + lane;          // 0..511
        int k0 = (task & 31) * 8;                 // 0..248
        float v[8];
        #pragma unroll
        for (int j = 0; j < 8; j++) v[j] = W1[(size_t)(k0 + j) * F1 + n];
        uint4 u;
        u.x = (uint)f2bf(v[0]) | ((uint)f2bf(v[1]) << 16);
        u.y = (uint)f2bf(v[2]) | ((uint)f2bf(v[3]) << 16);
        u.z = (uint)f2bf(v[4]) | ((uint)f2bf(v[5]) << 16);
        u.w = (uint)f2bf(v[6]) | ((uint)f2bf(v[7]) << 16);
        *(uint4*)&w1h[(size_t)n * D_IN + k0] = u;
    } else if (b <= 128) {
        // W2 [512][256] -> w2h [256][512]
        int task = (b - 65) * 4 + (tid >> 6);     // 0..255
        int lane = tid & 63;
        int n = (task >> 6) * 64 + lane;          // 0..255
        int k0 = (task & 63) * 8;                 // 0..504
        float v[8];
        #pragma unroll
        for (int j = 0; j < 8; j++) v[j] = W2[(size_t)(k0 + j) * D_OUT + n];
        uint4 u;
        u.x = (uint)f2bf(v[0]) | ((uint)f2bf(v[1]) << 16);
        u.y = (uint)f2bf(v[2]) | ((uint)f2bf(v[3]) << 16);
        u.z = (uint)f2bf(v[4]) | ((uint)f2bf(v[5]) << 16);
        u.w = (uint)f2bf(v[6]) | ((uint)f2bf(v[7]) << 16);
        *(uint4*)&w2h[(size_t)n * F1 + k0] = u;
    } else {
        // x f32 -> bf16, 8/thread
        int i8 = (b - 129) * 256 + tid;           // < 320000
        float4 a = *(const float4*)&x[(size_t)i8 * 8];
        float4 c = *(const float4*)&x[(size_t)i8 * 8 + 4];
        uint4 u;
        u.x = (uint)f2bf(a.x) | ((uint)f2bf(a.y) << 16);
        u.y = (uint)f2bf(a.z) | ((uint)f2bf(a.w) << 16);
        u.z = (uint)f2bf(c.x) | ((uint)f2bf(c.y) << 16);
        u.w = (uint)f2bf(c.z) | ((uint)f2bf(c.w) << 16);
        *(uint4*)&xb[(size_t)i8 * 8] = u;
    }
}

// ---------------- K4: scatter (atomic-free, rank-based) ----------------

__global__ __launch_bounds__(256) void k_scatter(const int* __restrict__ ei,
                                                 const int* __restrict__ row_start,
                                                 const int* __restrict__ rank,
                                                 int* __restrict__ csr_src) {
    int e = blockIdx.x * 256 + threadIdx.x;
    if (e < E_TOT) {
        int src = (e < E_RAW) ? ei[e] : (e - E_RAW);
        int dst = (e < E_RAW) ? ei[E_RAW + e] : (e - E_RAW);
        csr_src[row_start[dst] + rank[e]] = src;
    }
}

// ---------------- MFMA GEMM (single-buffer) + fused attn-dot epilogue ----------------

template<int BM, int KD, int ND, int WC, int HMUL>
__device__ __forceinline__ void gemm_attn(int bx, int by, int tid,
                                          const ushort* __restrict__ A,
                                          const ushort* __restrict__ B,
                                          ushort* __restrict__ C,
                                          const float* __restrict__ avs,
                                          const float* __restrict__ avd,
                                          float* __restrict__ os,
                                          float* __restrict__ od) {
    constexpr int WR = 4 / WC;
    constexpr int MI = (BM / WR) / 16;      // 4
    constexpr int NJ = (64 / WC) / 16;      // 2 (BM=128) or 1 (BM=64)
    __shared__ ushort sA[BM * 64];
    __shared__ ushort sB[64 * 64];

    const int lane = tid & 63;
    const int wid = tid >> 6;
    const int wr = wid / WC;
    const int wc = wid % WC;
    const int m0 = by * BM;
    const int n0 = bx * 64;
    const int fr = lane & 15;
    const int fs = lane >> 4;
    const int rowc = lane >> 3;
    const int slot = (lane & 7) ^ rowc;

    f32x4 acc[MI][NJ];
    #pragma unroll
    for (int i = 0; i < MI; i++)
        #pragma unroll
        for (int j = 0; j < NJ; j++) acc[i][j] = (f32x4){0.f, 0.f, 0.f, 0.f};

    for (int k0 = 0; k0 < KD; k0 += 64) {
        #pragma unroll
        for (int t = 0; t < BM / 32; t++) {
            int c = wid + 4 * t;
            int gr = m0 + c * 8 + rowc;
            gr = gr < N_NODES ? gr : N_NODES - 1;
            gload_lds16(A + (size_t)gr * KD + k0 + slot * 8, &sA[c * 512]);
        }
        #pragma unroll
        for (int t = 0; t < 2; t++) {
            int c = wid + 4 * t;
            gload_lds16(B + (size_t)(n0 + c * 8 + rowc) * KD + k0 + slot * 8, &sB[c * 512]);
        }
        __syncthreads();
        #pragma unroll
        for (int kk = 0; kk < 2; kk++) {
            int sbase = kk * 4 + fs;
            bf16x8 a_f[MI], b_f[NJ];
            #pragma unroll
            for (int i = 0; i < MI; i++) {
                int r = wr * 64 + i * 16 + fr;
                a_f[i] = *(const bf16x8*)&sA[r * 64 + ((sbase ^ (r & 7)) << 3)];
            }
            #pragma unroll
            for (int j = 0; j < NJ; j++) {
                int cc = wc * (64 / WC) + j * 16 + fr;
                b_f[j] = *(const bf16x8*)&sB[cc * 64 + ((sbase ^ (cc & 7)) << 3)];
            }
            #pragma unroll
            for (int i = 0; i < MI; i++)
                #pragma unroll
                for (int j = 0; j < NJ; j++)
                    acc[i][j] = __builtin_amdgcn_mfma_f32_16x16x32_bf16(a_f[i], b_f[j], acc[i][j], 0, 0, 0);
        }
        __syncthreads();
    }

    // epilogue: C/D layout col=lane&15, row=(lane>>4)*4+q
    const int hoff = (HMUL == 4) ? (n0 >> 7) : 0;
    float sv[NJ], dv[NJ];
    int cols[NJ];
    #pragma unroll
    for (int j = 0; j < NJ; j++) {
        cols[j] = n0 + wc * (64 / WC) + j * 16 + fr;
        sv[j] = avs[cols[j]];
        dv[j] = avd[cols[j]];
    }
    #pragma unroll
    for (int i = 0; i < MI; i++) {
        int row_base = m0 + wr * 64 + i * 16 + (fs << 2);
        float ps[4], pd[4];
        #pragma unroll
        for (int q = 0; q < 4; q++) {
            int r = row_base + q;
            float p_s = 0.f, p_d = 0.f;
            #pragma unroll
            for (int j = 0; j < NJ; j++) {
                float v = acc[i][j][q];
                if (r < N_NODES) C[(size_t)r * ND + cols[j]] = f2bf(v);
                p_s += v * sv[j];
                p_d += v * dv[j];
            }
            ps[q] = p_s; pd[q] = p_d;
        }
        #pragma unroll
        for (int q = 0; q < 4; q++) {
            #pragma unroll
            for (int m = 8; m >= 1; m >>= 1) {
                ps[q] += __shfl_xor(ps[q], m, 16);
                pd[q] += __shfl_xor(pd[q], m, 16);
            }
        }
        if (fr == 0) {
            #pragma unroll
            for (int q = 0; q < 4; q++) {
                int r = row_base + q;
                if (r < N_NODES) {
                    atomicAdd(&os[r * HMUL + hoff], ps[q]);
                    atomicAdd(&od[r * HMUL + hoff], pd[q]);
                }
            }
        }
    }
}

__global__ __launch_bounds__(256) void k_gemm1(const ushort* __restrict__ xb,
                                               const ushort* __restrict__ w1h,
                                               ushort* __restrict__ h1,
                                               const float* __restrict__ a1s,
                                               const float* __restrict__ a1d,
                                               float* __restrict__ as1,
                                               float* __restrict__ ad1) {
    int g = blockIdx.x;
    gemm_attn<128, D_IN, F1, 2, 4>(g % 8, g / 8, threadIdx.x,
                                   xb, w1h, h1, a1s, a1d, as1, ad1);
}

__global__ __launch_bounds__(256) void k_gemm2(const ushort* __restrict__ heluh,
                                               const ushort* __restrict__ w2h,
                                               ushort* __restrict__ h2,
                                               const float* __restrict__ a2s,
                                               const float* __restrict__ a2d,
                                               float* __restrict__ as2,
                                               float* __restrict__ ad2) {
    int b = blockIdx.x;
    gemm_attn<64, F1, D_OUT, 4, 1>(b % 4, b / 4, threadIdx.x,
                                   heluh, w2h, h2, a2s, a2d, as2, ad2);
}

// ---------------- edge aggregation ----------------

__device__ __forceinline__ void fma8(uint4 v, float e, float* acc) {
    acc[0] += bfu_lo(v.x) * e; acc[1] += bfu_hi(v.x) * e;
    acc[2] += bfu_lo(v.y) * e; acc[3] += bfu_hi(v.y) * e;
    acc[4] += bfu_lo(v.z) * e; acc[5] += bfu_hi(v.z) * e;
    acc[6] += bfu_lo(v.w) * e; acc[7] += bfu_hi(v.w) * e;
}

// K6: layer 1 — 1 node/block, 4 waves = 4 heads; 4-edge parity within each wave.
// 16-lane group (sub) handles one edge's 128-feat head slice (16 x 16B = 256B).
__global__ __launch_bounds__(256) void k_edge1(const int* __restrict__ row_start,
                                               const int* __restrict__ csr_src,
                                               const ushort* __restrict__ h1,
                                               const float* __restrict__ as1,
                                               const float* __restrict__ ad1,
                                               const float* __restrict__ b1,
                                               ushort* __restrict__ heluh) {
    int node = blockIdx.x;
    int head = threadIdx.x >> 6;
    int lane = threadIdx.x & 63;
    int sub  = lane >> 4;        // edge parity 0..3
    int fl   = lane & 15;        // 16B chunk within head slice
    int start = row_start[node];
    int end   = row_start[node + 1];

    const int fb = head * HID + fl * 8;
    float adl = ad1[node * 4 + head];

    float acc[8] = {0,0,0,0,0,0,0,0};
    float sum = 0.f;

    int i = start;
    for (; i + 16 <= end; i += 16) {
        int s[4];
        #pragma unroll
        for (int k = 0; k < 4; k++) s[k] = csr_src[i + 4 * k + sub];
        float l[4];
        #pragma unroll
        for (int k = 0; k < 4; k++) l[k] = as1[s[k] * 4 + head];
        uint4 v[4];
        #pragma unroll
        for (int k = 0; k < 4; k++) v[k] = *(const uint4*)(h1 + (size_t)s[k] * F1 + fb);
        #pragma unroll
        for (int k = 0; k < 4; k++) {
            float t = l[k] + adl;
            t = t > 0.f ? t : SLOPE * t;
            float e = __expf(t);
            sum += e;
            fma8(v[k], e, acc);
        }
    }
    for (; i < end; i += 4) {
        if (i + sub < end) {
            int s0 = csr_src[i + sub];
            float t = as1[s0 * 4 + head] + adl;
            uint4 v0 = *(const uint4*)(h1 + (size_t)s0 * F1 + fb);
            t = t > 0.f ? t : SLOPE * t;
            float e = __expf(t);
            sum += e;
            fma8(v0, e, acc);
        }
    }
    // merge 4 edge-parity groups (lanes with equal fl)
    #pragma unroll
    for (int m = 16; m <= 32; m <<= 1) {
        #pragma unroll
        for (int j = 0; j < 8; j++) acc[j] += __shfl_xor(acc[j], m, 64);
        sum += __shfl_xor(sum, m, 64);
    }
    float inv = 1.f / sum;

    if (sub == 0) {
        size_t o = (size_t)node * F1 + fb;
        const float* bp = b1 + fb;
        uint pk[4];
        #pragma unroll
        for (int j = 0; j < 4; j++) {
            float v0 = acc[2*j]   * inv + bp[2*j];
            float v1 = acc[2*j+1] * inv + bp[2*j+1];
            v0 = v0 > 0.f ? v0 : (__expf(v0) - 1.f);
            v1 = v1 > 0.f ? v1 : (__expf(v1) - 1.f);
            pk[j] = (uint)f2bf(v0) | ((uint)f2bf(v1) << 16);
        }
        *(uint4*)&heluh[o] = make_uint4(pk[0], pk[1], pk[2], pk[3]);
    }
}

// K7: layer 2 — 2 nodes/block, 2 waves/node (128 feats each); 4-edge parity.
__global__ __launch_bounds__(256) void k_edge2(const int* __restrict__ row_start,
                                               const int* __restrict__ csr_src,
                                               const ushort* __restrict__ h2,
                                               const float* __restrict__ as2,
                                               const float* __restrict__ ad2,
                                               const float* __restrict__ b2,
                                               float* __restrict__ out) {
    int node = blockIdx.x * 2 + (threadIdx.x >> 7);
    int w    = (threadIdx.x >> 6) & 1;   // feature half
    int lane = threadIdx.x & 63;
    int sub  = lane >> 4;
    int fl   = lane & 15;
    int start = row_start[node];
    int end   = row_start[node + 1];

    const int fb = w * 128 + fl * 8;
    float ad = ad2[node];

    float acc[8] = {0,0,0,0,0,0,0,0};
    float sum = 0.f;

    int i = start;
    for (; i + 16 <= end; i += 16) {
        int s[4];
        #pragma unroll
        for (int k = 0; k < 4; k++) s[k] = csr_src[i + 4 * k + sub];
        float l[4];
        #pragma unroll
        for (int k = 0; k < 4; k++) l[k] = as2[s[k]];
        uint4 v[4];
        #pragma unroll
        for (int k = 0; k < 4; k++) v[k] = *(const uint4*)(h2 + (size_t)s[k] * D_OUT + fb);
        #pragma unroll
        for (int k = 0; k < 4; k++) {
            float t = l[k] + ad;
            t = t > 0.f ? t : SLOPE * t;
            float e = __expf(t);
            sum += e;
            fma8(v[k], e, acc);
        }
    }
    for (; i < end; i += 4) {
        if (i + sub < end) {
            int s0 = csr_src[i + sub];
            float t = as2[s0] + ad;
            uint4 v0 = *(const uint4*)(h2 + (size_t)s0 * D_OUT + fb);
            t = t > 0.f ? t : SLOPE * t;
            float e = __expf(t);
            sum += e;
            fma8(v0, e, acc);
        }
    }
    #pragma unroll
    for (int m = 16; m <= 32; m <<= 1) {
        #pragma unroll
        for (int j = 0; j < 8; j++) acc[j] += __shfl_xor(acc[j], m, 64);
        sum += __shfl_xor(sum, m, 64);
    }
    float inv = 1.f / sum;

    if (sub == 0) {
        size_t o = (size_t)node * D_OUT + fb;
        const float* bp = b2 + fb;
        float4 r0, r1;
        r0.x = acc[0] * inv + bp[0]; r0.y = acc[1] * inv + bp[1];
        r0.z = acc[2] * inv + bp[2]; r0.w = acc[3] * inv + bp[3];
        r1.x = acc[4] * inv + bp[4]; r1.y = acc[5] * inv + bp[5];
        r1.z = acc[6] * inv + bp[6]; r1.w = acc[7] * inv + bp[7];
        *(float4*)&out[o] = r0;
        *(float4*)&out[o + 4] = r1;
    }
}

// ---------------- launch ----------------

extern "C" void kernel_launch(void* const* d_in, const int* in_sizes, int n_in,
                              void* d_out, int out_size, void* d_ws, size_t ws_size,
                              hipStream_t stream) {
    const float* x   = (const float*)d_in[0];
    const int*   ei  = (const int*)d_in[1];
    const float* W1  = (const float*)d_in[2];
    const float* a1s = (const float*)d_in[3];
    const float* a1d = (const float*)d_in[4];
    const float* b1  = (const float*)d_in[5];
    const float* W2  = (const float*)d_in[6];
    const float* a2s = (const float*)d_in[7];
    const float* a2d = (const float*)d_in[8];
    const float* b2  = (const float*)d_in[9];
    float* out = (float*)d_out;

    char* ws = (char*)d_ws;
    size_t off = 0;
    auto take = [&](size_t bytes) {
        char* p = ws + off;
        off += (bytes + 255) & ~(size_t)255;
        return p;
    };
    int*    deg       = (int*)take(sizeof(int) * N_NODES);
    int*    rank      = (int*)take(sizeof(int) * E_TOT);
    int*    row_start = (int*)take(sizeof(int) * (N_NODES + 1));
    int*    csr_src   = (int*)take(sizeof(int) * E_TOT);
    ushort* xb        = (ushort*)take(sizeof(ushort) * (size_t)N_NODES * D_IN);
    ushort* w1h       = (ushort*)take(sizeof(ushort) * D_IN * F1);
    ushort* w2h       = (ushort*)take(sizeof(ushort) * F1 * D_OUT);
    ushort* h1        = (ushort*)take(sizeof(ushort) * (size_t)N_NODES * F1);
    float*  as1       = (float*)take(sizeof(float) * N_NODES * 4);
    float*  ad1       = (float*)take(sizeof(float) * N_NODES * 4);
    ushort* heluh     = (ushort*)take(sizeof(ushort) * (size_t)N_NODES * F1);
    ushort* h2        = (ushort*)take(sizeof(ushort) * (size_t)N_NODES * D_OUT);
    float*  as2       = (float*)take(sizeof(float) * N_NODES);
    float*  ad2       = (float*)take(sizeof(float) * N_NODES);

    k_zero_all<<<(4 * N_NODES + 255) / 256, 256, 0, stream>>>(deg, as1, ad1, as2, ad2);
    k_hist<<<EBLOCKS, 256, 0, stream>>>(ei, deg, rank);
    k_prep<<<1379, 256, 0, stream>>>(deg, row_start, W1, w1h, W2, w2h, x, xb);
    k_scatter<<<EBLOCKS, 256, 0, stream>>>(ei, row_start, rank, csr_src);
    k_gemm1<<<8 * 79, 256, 0, stream>>>(xb, w1h, h1, a1s, a1d, as1, ad1);
    k_edge1<<<N_NODES, 256, 0, stream>>>(row_start, csr_src, h1, as1, ad1, b1, heluh);
    k_gemm2<<<4 * 157, 256, 0, stream>>>(heluh, w2h, h2, a2s, a2d, as2, ad2);
    k_edge2<<<N_NODES / 2, 256, 0, stream>>>(row_start, csr_src, h2, as2, ad2, b2, out);
}

// Round 11
// 149.154 us; speedup vs baseline: 1.0506x; 1.0506x over previous
//
#include <hip/hip_runtime.h>

#define N_NODES 10000
#define E_RAW   320000
#define E_TOT   330000
#define D_IN    256
#define HID     128
#define F1      512
#define D_OUT   256
#define SLOPE   0.2f
#define EBLOCKS 1290  // ceil(E_TOT/256)
#define G1_TILES 632  // 8 * 79
#define SCAN_CHUNK 40 // 256*40 >= N_NODES

typedef __attribute__((ext_vector_type(8))) short bf16x8;
typedef __attribute__((ext_vector_type(4))) float f32x4;

__device__ __forceinline__ float bf2f(ushort u) {
    return __uint_as_float(((uint)u) << 16);
}
__device__ __forceinline__ ushort f2bf(float x) {
    uint u = __float_as_uint(x);
    uint r = (u + 0x7FFFu + ((u >> 16) & 1u)) >> 16;
    return (ushort)r;
}
__device__ __forceinline__ float bfu_lo(uint u) { return __uint_as_float(u << 16); }
__device__ __forceinline__ float bfu_hi(uint u) { return __uint_as_float(u & 0xFFFF0000u); }

__device__ __forceinline__ void gload_lds16(const void* g, void* l) {
    __builtin_amdgcn_global_load_lds(
        (const __attribute__((address_space(1))) void*)g,
        (__attribute__((address_space(3))) void*)l, 16, 0, 0);
}

// ---------------- K1: zero scratch ----------------

__global__ __launch_bounds__(256) void k_zero_all(int* __restrict__ deg,
                                                  float* __restrict__ as1,
                                                  float* __restrict__ ad1,
                                                  float* __restrict__ as2,
                                                  float* __restrict__ ad2) {
    int i = blockIdx.x * 256 + threadIdx.x;
    if (i < 4 * N_NODES) { as1[i] = 0.f; ad1[i] = 0.f; }
    if (i < N_NODES) { deg[i] = 0; as2[i] = 0.f; ad2[i] = 0.f; }
}

// ---------------- K2: degree histogram + per-edge rank ----------------

__global__ __launch_bounds__(256) void k_hist(const int* __restrict__ ei,
                                              int* __restrict__ deg,
                                              int* __restrict__ rank) {
    int e = blockIdx.x * 256 + threadIdx.x;
    if (e < E_TOT) {
        int dst = (e < E_RAW) ? ei[E_RAW + e] : (e - E_RAW);
        rank[e] = atomicAdd(&deg[dst], 1);
    }
}

// ---------------- K3: scan (block 0) + coalesced weight transposes + x cast ----------------

__global__ __launch_bounds__(256) void k_prep(const int* __restrict__ deg,
                                              int* __restrict__ row_start,
                                              const float* __restrict__ W1,
                                              ushort* __restrict__ w1h,
                                              const float* __restrict__ W2,
                                              ushort* __restrict__ w2h,
                                              const float* __restrict__ x,
                                              ushort* __restrict__ xb) {
    int b = blockIdx.x;
    int tid = threadIdx.x;
    if (b == 0) {
        __shared__ int tots[256];
        int base = tid * SCAN_CHUNK;
        int loc[SCAN_CHUNK];
        int s = 0;
        #pragma unroll
        for (int k = 0; k < SCAN_CHUNK; k++) {
            int idx = base + k;
            int v = (idx < N_NODES) ? deg[idx] : 0;
            loc[k] = s;
            s += v;
        }
        tots[tid] = s;
        __syncthreads();
        for (int off = 1; off < 256; off <<= 1) {
            int t = (tid >= off) ? tots[tid - off] : 0;
            __syncthreads();
            tots[tid] += t;
            __syncthreads();
        }
        int excl = tots[tid] - s;
        #pragma unroll
        for (int k = 0; k < SCAN_CHUNK; k++) {
            int idx = base + k;
            if (idx < N_NODES) row_start[idx] = excl + loc[k];
        }
        if (tid == 255) row_start[N_NODES] = E_TOT;
    } else if (b <= 64) {
        // W1 [256][512] -> w1h [512][256]; wave task: 64 cols x 8 rows
        int task = (b - 1) * 4 + (tid >> 6);      // 0..255
        int lane = tid & 63;
        int n = (task >> 5) * 64 + lane;          // 0..511
        int k0 = (task & 31) * 8;                 // 0..248
        float v[8];
        #pragma unroll
        for (int j = 0; j < 8; j++) v[j] = W1[(size_t)(k0 + j) * F1 + n];
        uint4 u;
        u.x = (uint)f2bf(v[0]) | ((uint)f2bf(v[1]) << 16);
        u.y = (uint)f2bf(v[2]) | ((uint)f2bf(v[3]) << 16);
        u.z = (uint)f2bf(v[4]) | ((uint)f2bf(v[5]) << 16);
        u.w = (uint)f2bf(v[6]) | ((uint)f2bf(v[7]) << 16);
        *(uint4*)&w1h[(size_t)n * D_IN + k0] = u;
    } else if (b <= 128) {
        // W2 [512][256] -> w2h [256][512]
        int task = (b - 65) * 4 + (tid >> 6);     // 0..255
        int lane = tid & 63;
        int n = (task >> 6) * 64 + lane;          // 0..255
        int k0 = (task & 63) * 8;                 // 0..504
        float v[8];
        #pragma unroll
        for (int j = 0; j < 8; j++) v[j] = W2[(size_t)(k0 + j) * D_OUT + n];
        uint4 u;
        u.x = (uint)f2bf(v[0]) | ((uint)f2bf(v[1]) << 16);
        u.y = (uint)f2bf(v[2]) | ((uint)f2bf(v[3]) << 16);
        u.z = (uint)f2bf(v[4]) | ((uint)f2bf(v[5]) << 16);
        u.w = (uint)f2bf(v[6]) | ((uint)f2bf(v[7]) << 16);
        *(uint4*)&w2h[(size_t)n * F1 + k0] = u;
    } else {
        // x f32 -> bf16, 8/thread
        int i8 = (b - 129) * 256 + tid;           // < 320000
        float4 a = *(const float4*)&x[(size_t)i8 * 8];
        float4 c = *(const float4*)&x[(size_t)i8 * 8 + 4];
        uint4 u;
        u.x = (uint)f2bf(a.x) | ((uint)f2bf(a.y) << 16);
        u.y = (uint)f2bf(a.z) | ((uint)f2bf(a.w) << 16);
        u.z = (uint)f2bf(c.x) | ((uint)f2bf(c.y) << 16);
        u.w = (uint)f2bf(c.z) | ((uint)f2bf(c.w) << 16);
        *(uint4*)&xb[(size_t)i8 * 8] = u;
    }
}

// ---------------- MFMA GEMM (single-buffer) + fused attn-dot epilogue ----------------

template<int BM, int KD, int ND, int WC, int HMUL>
__device__ __forceinline__ void gemm_attn(int bx, int by, int tid,
                                          const ushort* __restrict__ A,
                                          const ushort* __restrict__ B,
                                          ushort* __restrict__ C,
                                          const float* __restrict__ avs,
                                          const float* __restrict__ avd,
                                          float* __restrict__ os,
                                          float* __restrict__ od) {
    constexpr int WR = 4 / WC;
    constexpr int MI = (BM / WR) / 16;      // 4
    constexpr int NJ = (64 / WC) / 16;      // 2 (BM=128) or 1 (BM=64)
    __shared__ ushort sA[BM * 64];
    __shared__ ushort sB[64 * 64];

    const int lane = tid & 63;
    const int wid = tid >> 6;
    const int wr = wid / WC;
    const int wc = wid % WC;
    const int m0 = by * BM;
    const int n0 = bx * 64;
    const int fr = lane & 15;
    const int fs = lane >> 4;
    const int rowc = lane >> 3;
    const int slot = (lane & 7) ^ rowc;

    f32x4 acc[MI][NJ];
    #pragma unroll
    for (int i = 0; i < MI; i++)
        #pragma unroll
        for (int j = 0; j < NJ; j++) acc[i][j] = (f32x4){0.f, 0.f, 0.f, 0.f};

    for (int k0 = 0; k0 < KD; k0 += 64) {
        #pragma unroll
        for (int t = 0; t < BM / 32; t++) {
            int c = wid + 4 * t;
            int gr = m0 + c * 8 + rowc;
            gr = gr < N_NODES ? gr : N_NODES - 1;
            gload_lds16(A + (size_t)gr * KD + k0 + slot * 8, &sA[c * 512]);
        }
        #pragma unroll
        for (int t = 0; t < 2; t++) {
            int c = wid + 4 * t;
            gload_lds16(B + (size_t)(n0 + c * 8 + rowc) * KD + k0 + slot * 8, &sB[c * 512]);
        }
        __syncthreads();
        #pragma unroll
        for (int kk = 0; kk < 2; kk++) {
            int sbase = kk * 4 + fs;
            bf16x8 a_f[MI], b_f[NJ];
            #pragma unroll
            for (int i = 0; i < MI; i++) {
                int r = wr * 64 + i * 16 + fr;
                a_f[i] = *(const bf16x8*)&sA[r * 64 + ((sbase ^ (r & 7)) << 3)];
            }
            #pragma unroll
            for (int j = 0; j < NJ; j++) {
                int cc = wc * (64 / WC) + j * 16 + fr;
                b_f[j] = *(const bf16x8*)&sB[cc * 64 + ((sbase ^ (cc & 7)) << 3)];
            }
            #pragma unroll
            for (int i = 0; i < MI; i++)
                #pragma unroll
                for (int j = 0; j < NJ; j++)
                    acc[i][j] = __builtin_amdgcn_mfma_f32_16x16x32_bf16(a_f[i], b_f[j], acc[i][j], 0, 0, 0);
        }
        __syncthreads();
    }

    // epilogue: C/D layout col=lane&15, row=(lane>>4)*4+q
    const int hoff = (HMUL == 4) ? (n0 >> 7) : 0;
    float sv[NJ], dv[NJ];
    int cols[NJ];
    #pragma unroll
    for (int j = 0; j < NJ; j++) {
        cols[j] = n0 + wc * (64 / WC) + j * 16 + fr;
        sv[j] = avs[cols[j]];
        dv[j] = avd[cols[j]];
    }
    #pragma unroll
    for (int i = 0; i < MI; i++) {
        int row_base = m0 + wr * 64 + i * 16 + (fs << 2);
        float ps[4], pd[4];
        #pragma unroll
        for (int q = 0; q < 4; q++) {
            int r = row_base + q;
            float p_s = 0.f, p_d = 0.f;
            #pragma unroll
            for (int j = 0; j < NJ; j++) {
                float v = acc[i][j][q];
                if (r < N_NODES) C[(size_t)r * ND + cols[j]] = f2bf(v);
                p_s += v * sv[j];
                p_d += v * dv[j];
            }
            ps[q] = p_s; pd[q] = p_d;
        }
        #pragma unroll
        for (int q = 0; q < 4; q++) {
            #pragma unroll
            for (int m = 8; m >= 1; m >>= 1) {
                ps[q] += __shfl_xor(ps[q], m, 16);
                pd[q] += __shfl_xor(pd[q], m, 16);
            }
        }
        if (fr == 0) {
            #pragma unroll
            for (int q = 0; q < 4; q++) {
                int r = row_base + q;
                if (r < N_NODES) {
                    atomicAdd(&os[r * HMUL + hoff], ps[q]);
                    atomicAdd(&od[r * HMUL + hoff], pd[q]);
                }
            }
        }
    }
}

// ---------------- K4: GEMM1(+attn1) with scatter blocks riding along ----------------

__global__ __launch_bounds__(256) void k_g1s(const ushort* __restrict__ xb,
                                             const ushort* __restrict__ w1h,
                                             ushort* __restrict__ h1,
                                             const float* __restrict__ a1s,
                                             const float* __restrict__ a1d,
                                             float* __restrict__ as1,
                                             float* __restrict__ ad1,
                                             const int* __restrict__ ei,
                                             const int* __restrict__ row_start,
                                             const int* __restrict__ rank,
                                             int* __restrict__ csr_src) {
    int b = blockIdx.x;
    if (b < G1_TILES) {
        gemm_attn<128, D_IN, F1, 2, 4>(b % 8, b / 8, threadIdx.x,
                                       xb, w1h, h1, a1s, a1d, as1, ad1);
        return;
    }
    int e = (b - G1_TILES) * 256 + threadIdx.x;
    if (e < E_TOT) {
        int src = (e < E_RAW) ? ei[e] : (e - E_RAW);
        int dst = (e < E_RAW) ? ei[E_RAW + e] : (e - E_RAW);
        csr_src[row_start[dst] + rank[e]] = src;
    }
}

__global__ __launch_bounds__(256) void k_gemm2(const ushort* __restrict__ heluh,
                                               const ushort* __restrict__ w2h,
                                               ushort* __restrict__ h2,
                                               const float* __restrict__ a2s,
                                               const float* __restrict__ a2d,
                                               float* __restrict__ as2,
                                               float* __restrict__ ad2) {
    int b = blockIdx.x;
    gemm_attn<64, F1, D_OUT, 4, 1>(b % 4, b / 4, threadIdx.x,
                                   heluh, w2h, h2, a2s, a2d, as2, ad2);
}

// ---------------- edge aggregation (R9-verbatim structures) ----------------

__device__ __forceinline__ void fma8(uint4 v, float e, float* acc) {
    acc[0] += bfu_lo(v.x) * e; acc[1] += bfu_hi(v.x) * e;
    acc[2] += bfu_lo(v.y) * e; acc[3] += bfu_hi(v.y) * e;
    acc[4] += bfu_lo(v.z) * e; acc[5] += bfu_hi(v.z) * e;
    acc[6] += bfu_lo(v.w) * e; acc[7] += bfu_hi(v.w) * e;
}

// K5: layer 1 — 2 nodes/block, 2 waves/node (2 heads each), 2 edges/iter.
__global__ __launch_bounds__(256) void k_edge1(const int* __restrict__ row_start,
                                               const int* __restrict__ csr_src,
                                               const ushort* __restrict__ h1,
                                               const float* __restrict__ as1,
                                               const float* __restrict__ ad1,
                                               const float* __restrict__ b1,
                                               ushort* __restrict__ heluh) {
    int node = blockIdx.x * 2 + (threadIdx.x >> 7);
    int wid2 = (threadIdx.x >> 6) & 1;       // feature-half index
    int lane = threadIdx.x & 63;
    int sub  = lane >> 5;
    int fl   = lane & 31;
    int start = row_start[node];
    int end   = row_start[node + 1];

    const int fb   = wid2 * 256 + fl * 8;    // feature base (elements)
    const int head = fb >> 7;                // 0..3
    float adl = ad1[node * 4 + head];

    float acc[8] = {0,0,0,0,0,0,0,0};
    float sum = 0.f;

    int i = start;
    for (; i + 8 <= end; i += 8) {
        int s[4];
        #pragma unroll
        for (int k = 0; k < 4; k++) s[k] = csr_src[i + 2 * k + sub];
        float l[4];
        #pragma unroll
        for (int k = 0; k < 4; k++) l[k] = as1[s[k] * 4 + head];
        uint4 v[4];
        #pragma unroll
        for (int k = 0; k < 4; k++) v[k] = *(const uint4*)(h1 + (size_t)s[k] * F1 + fb);
        #pragma unroll
        for (int k = 0; k < 4; k++) {
            float t = l[k] + adl;
            t = t > 0.f ? t : SLOPE * t;
            float e = __expf(t);
            sum += e;
            fma8(v[k], e, acc);
        }
    }
    for (; i < end; i += 2) {
        if (i + sub < end) {
            int s0 = csr_src[i + sub];
            float t = as1[s0 * 4 + head] + adl;
            uint4 v0 = *(const uint4*)(h1 + (size_t)s0 * F1 + fb);
            t = t > 0.f ? t : SLOPE * t;
            float e = __expf(t);
            sum += e;
            fma8(v0, e, acc);
        }
    }
    // merge edge-parity halves
    #pragma unroll
    for (int j = 0; j < 8; j++) acc[j] += __shfl_xor(acc[j], 32, 64);
    sum += __shfl_xor(sum, 32, 64);
    float inv = 1.f / sum;

    if (lane < 32) {
        size_t o = (size_t)node * F1 + fb;
        const float* bp = b1 + fb;
        uint pk[4];
        #pragma unroll
        for (int j = 0; j < 4; j++) {
            float v0 = acc[2*j]   * inv + bp[2*j];
            float v1 = acc[2*j+1] * inv + bp[2*j+1];
            v0 = v0 > 0.f ? v0 : (__expf(v0) - 1.f);
            v1 = v1 > 0.f ? v1 : (__expf(v1) - 1.f);
            pk[j] = (uint)f2bf(v0) | ((uint)f2bf(v1) << 16);
        }
        *(uint4*)&heluh[o] = make_uint4(pk[0], pk[1], pk[2], pk[3]);
    }
}

// K7: layer 2 — 4 nodes/block; 2 edges/wave-iter, 32 lanes x 16B per edge
__global__ __launch_bounds__(256) void k_edge2(const int* __restrict__ row_start,
                                               const int* __restrict__ csr_src,
                                               const ushort* __restrict__ h2,
                                               const float* __restrict__ as2,
                                               const float* __restrict__ ad2,
                                               const float* __restrict__ b2,
                                               float* __restrict__ out) {
    int node = blockIdx.x * 4 + (threadIdx.x >> 6);
    int lane = threadIdx.x & 63;
    int sub = lane >> 5;
    int fl  = lane & 31;
    int start = row_start[node];
    int end   = row_start[node + 1];

    float ad = ad2[node];
    float acc[8] = {0,0,0,0,0,0,0,0};
    float sum = 0.f;
    const size_t fo = (size_t)fl * 8;

    int i = start;
    for (; i + 8 <= end; i += 8) {
        int s[4];
        #pragma unroll
        for (int k = 0; k < 4; k++) s[k] = csr_src[i + 2 * k + sub];
        float l[4];
        #pragma unroll
        for (int k = 0; k < 4; k++) l[k] = as2[s[k]];
        uint4 v[4];
        #pragma unroll
        for (int k = 0; k < 4; k++) v[k] = *(const uint4*)(h2 + (size_t)s[k] * D_OUT + fo);
        #pragma unroll
        for (int k = 0; k < 4; k++) {
            float t = l[k] + ad;
            t = t > 0.f ? t : SLOPE * t;
            float e = __expf(t);
            sum += e;
            fma8(v[k], e, acc);
        }
    }
    for (; i < end; i += 2) {
        if (i + sub < end) {
            int s0 = csr_src[i + sub];
            float t = as2[s0] + ad;
            uint4 v0 = *(const uint4*)(h2 + (size_t)s0 * D_OUT + fo);
            t = t > 0.f ? t : SLOPE * t;
            float e = __expf(t);
            sum += e;
            fma8(v0, e, acc);
        }
    }
    #pragma unroll
    for (int j = 0; j < 8; j++) acc[j] += __shfl_xor(acc[j], 32, 64);
    sum += __shfl_xor(sum, 32, 64);
    float inv = 1.f / sum;

    if (lane < 32) {
        size_t o = (size_t)node * D_OUT + fo;
        const float* bp = b2 + fo;
        float4 r0, r1;
        r0.x = acc[0] * inv + bp[0]; r0.y = acc[1] * inv + bp[1];
        r0.z = acc[2] * inv + bp[2]; r0.w = acc[3] * inv + bp[3];
        r1.x = acc[4] * inv + bp[4]; r1.y = acc[5] * inv + bp[5];
        r1.z = acc[6] * inv + bp[6]; r1.w = acc[7] * inv + bp[7];
        *(float4*)&out[o] = r0;
        *(float4*)&out[o + 4] = r1;
    }
}

// ---------------- launch ----------------

extern "C" void kernel_launch(void* const* d_in, const int* in_sizes, int n_in,
                              void* d_out, int out_size, void* d_ws, size_t ws_size,
                              hipStream_t stream) {
    const float* x   = (const float*)d_in[0];
    const int*   ei  = (const int*)d_in[1];
    const float* W1  = (const float*)d_in[2];
    const float* a1s = (const float*)d_in[3];
    const float* a1d = (const float*)d_in[4];
    const float* b1  = (const float*)d_in[5];
    const float* W2  = (const float*)d_in[6];
    const float* a2s = (const float*)d_in[7];
    const float* a2d = (const float*)d_in[8];
    const float* b2  = (const float*)d_in[9];
    float* out = (float*)d_out;

    char* ws = (char*)d_ws;
    size_t off = 0;
    auto take = [&](size_t bytes) {
        char* p = ws + off;
        off += (bytes + 255) & ~(size_t)255;
        return p;
    };
    int*    deg       = (int*)take(sizeof(int) * N_NODES);
    int*    rank      = (int*)take(sizeof(int) * E_TOT);
    int*    row_start = (int*)take(sizeof(int) * (N_NODES + 1));
    int*    csr_src   = (int*)take(sizeof(int) * E_TOT);
    ushort* xb        = (ushort*)take(sizeof(ushort) * (size_t)N_NODES * D_IN);
    ushort* w1h       = (ushort*)take(sizeof(ushort) * D_IN * F1);
    ushort* w2h       = (ushort*)take(sizeof(ushort) * F1 * D_OUT);
    ushort* h1        = (ushort*)take(sizeof(ushort) * (size_t)N_NODES * F1);
    float*  as1       = (float*)take(sizeof(float) * N_NODES * 4);
    float*  ad1       = (float*)take(sizeof(float) * N_NODES * 4);
    ushort* heluh     = (ushort*)take(sizeof(ushort) * (size_t)N_NODES * F1);
    ushort* h2        = (ushort*)take(sizeof(ushort) * (size_t)N_NODES * D_OUT);
    float*  as2       = (float*)take(sizeof(float) * N_NODES);
    float*  ad2       = (float*)take(sizeof(float) * N_NODES);

    k_zero_all<<<(4 * N_NODES + 255) / 256, 256, 0, stream>>>(deg, as1, ad1, as2, ad2);
    k_hist<<<EBLOCKS, 256, 0, stream>>>(ei, deg, rank);
    k_prep<<<1379, 256, 0, stream>>>(deg, row_start, W1, w1h, W2, w2h, x, xb);
    k_g1s<<<G1_TILES + EBLOCKS, 256, 0, stream>>>(xb, w1h, h1, a1s, a1d, as1, ad1,
                                                  ei, row_start, rank, csr_src);
    k_edge1<<<N_NODES / 2, 256, 0, stream>>>(row_start, csr_src, h1, as1, ad1, b1, heluh);
    k_gemm2<<<4 * 157, 256, 0, stream>>>(heluh, w2h, h2, a2s, a2d, as2, ad2);
    k_edge2<<<N_NODES / 4, 256, 0, stream>>>(row_start, csr_src, h2, as2, ad2, b2, out);
}